// Round 1
// baseline (202.974 us; speedup 1.0000x reference)
//
#include <hip/hip_runtime.h>

#define NA 4096
#define HS 128
#define PSTR 72    // attn P-buffer row stride (bf16 elems)
#define CSTR 136   // proj/reduce LDS row stride (bf16 elems)

typedef unsigned short u16;
typedef unsigned long long u64;
using bf16x8  = __attribute__((ext_vector_type(8))) short;
using f32x4   = __attribute__((ext_vector_type(4))) float;
using ushort8 = __attribute__((ext_vector_type(8))) unsigned short;

// 1/sqrt(dk)=0.25 * log2(e) * 0.5 (K-dim duplication in the 16x16x32 MFMA)
#define QSCALE 0.18033688011112042f

static __device__ __forceinline__ u16 f2bf(float f) {
    unsigned u = __builtin_bit_cast(unsigned, f);
    u += 0x7FFFu + ((u >> 16) & 1u);
    return (u16)(u >> 16);
}

// ---------------------------------------------------------------------------
// Kernel 0a (blocks 0..63): weights -> bf16 in MFMA-fragment order:
//   Wf[mat][j0(8)][kk(4)][c(16)][q(4)][8]  (16384 elems per mat)
// Kernel 0b (blocks 64..1087): ballot-pack mask -> Mp[row(4096)][word(64)] u64
//   (pure-BW 64 MB read; removes the mask read + ballot prologue from attn)
// ---------------------------------------------------------------------------
__global__ __launch_bounds__(256) void cvt_w(
    const float* __restrict__ Wq, const float* __restrict__ Wk,
    const float* __restrict__ Wv, const float* __restrict__ Wo,
    const float* __restrict__ bq, const float* __restrict__ bk,
    const float* __restrict__ bv, const int* __restrict__ mask,
    u16* __restrict__ Wf, float* __restrict__ bb, u64* __restrict__ Mp)
{
    const int bx = blockIdx.x;
    const int t = threadIdx.x;
    if (bx < 64) {
        const int gid = bx * 256 + t;   // 16384 threads
        const int e = gid * 4;
        const int mat = e >> 14, off = e & 16383;
        const float* src = (mat == 0) ? Wq : (mat == 1) ? Wk : (mat == 2) ? Wv : Wo;
        const float s = (mat == 0) ? QSCALE : 1.0f;
        float4 v = *(const float4*)(src + off);
        ushort4 o;
        o.x = f2bf(v.x * s); o.y = f2bf(v.y * s);
        o.z = f2bf(v.z * s); o.w = f2bf(v.w * s);
        const int j = off >> 7, k0 = off & 127;
        const int j0 = j >> 4, c = j & 15, kk = k0 >> 5, q = (k0 >> 3) & 3;
        const int tgt = mat * 16384 + ((j0 * 4 + kk) * 16 + c) * 32 + q * 8 + (k0 & 7);
        *(ushort4*)(Wf + tgt) = o;
        if (gid < 128)      bb[gid] = bq[gid] * QSCALE;
        else if (gid < 256) bb[gid] = bk[gid - 128];
        else if (gid < 384) bb[gid] = bv[gid - 256];
    } else {
        const int mb = bx - 64;                 // 0..1023
        const int wv = t >> 6, lane = t & 63;
        const int row = mb * 4 + wv;            // one mask row per wave
        const int* mrow = mask + (size_t)row * NA;
        u64* orow = Mp + (size_t)row * 64;
#pragma unroll 8
        for (int w = 0; w < 64; ++w) {
            u64 b = __ballot(mrow[w * 64 + lane] != 0);
            if (lane == 0) orow[w] = b;
        }
    }
}

// ---------------------------------------------------------------------------
// Kernel 1: Q/K/V projections via MFMA. Block = 256 thr (4 waves) = 32 rows.
// Outputs:
//   Qbh/Kbh [head][4096][16]  (head-major: attn fragment loads contiguous)
//   VtB     [kb(64)][dim(128)][key(64)]  (PV fragment loads contiguous)
// ---------------------------------------------------------------------------
__global__ __launch_bounds__(256) void proj_mfma(
    const float* __restrict__ Xq, const float* __restrict__ Xk, const float* __restrict__ Xv,
    const u16* __restrict__ Wf, const float* __restrict__ bb,
    u16* __restrict__ Qbh, u16* __restrict__ Kbh, u16* __restrict__ VtB)
{
    const int mat = blockIdx.y;
    const float* X = (mat == 0) ? Xq : (mat == 1) ? Xk : Xv;
    const u16* Wm = Wf + mat * 16384;
    const float* bm = bb + mat * 128;
    const int r0b = blockIdx.x * 32;

    __shared__ __align__(16) u16 Xs[32 * CSTR];
    __shared__ __align__(16) u16 Cs[32 * CSTR];

    const int t = threadIdx.x;

    // stage X coalesced: thread -> row t>>3, 16 cols at (t&7)*16
    {
        const int r = t >> 3, cb = (t & 7) * 16;
        const float* Xr = X + (size_t)(r0b + r) * HS + cb;
#pragma unroll
        for (int seg = 0; seg < 4; ++seg) {
            float4 f = *(const float4*)(Xr + seg * 4);
            ushort4 u;
            u.x = f2bf(f.x); u.y = f2bf(f.y); u.z = f2bf(f.z); u.w = f2bf(f.w);
            *(ushort4*)(Xs + r * CSTR + cb + seg * 4) = u;
        }
    }
    __syncthreads();

    const int wv = t >> 6, lane = t & 63;
    const int c = lane & 15, q = lane >> 4;
    const int rw = (wv & 1) * 16;        // wave row offset in block
    const int j0b = (wv >> 1) * 4;       // wave col group (4 j0 of 16 cols)

    bf16x8 af[4];
#pragma unroll
    for (int kk = 0; kk < 4; ++kk)
        af[kk] = *(const bf16x8*)(Xs + (rw + c) * CSTR + kk * 32 + q * 8);

    const f32x4 zero = {0.f, 0.f, 0.f, 0.f};
#pragma unroll
    for (int jj = 0; jj < 4; ++jj) {
        const int j0 = j0b + jj;
        f32x4 acc = zero;
#pragma unroll
        for (int kk = 0; kk < 4; ++kk) {
            bf16x8 bf = *(const bf16x8*)(Wm + (j0 * 4 + kk) * 512 + c * 32 + q * 8);
            acc = __builtin_amdgcn_mfma_f32_16x16x32_bf16(af[kk], bf, acc, 0, 0, 0);
        }
        const float bias = bm[j0 * 16 + c];
#pragma unroll
        for (int r = 0; r < 4; ++r)
            Cs[(rw + 4 * q + r) * CSTR + j0 * 16 + c] = f2bf(acc[r] + bias);
    }
    __syncthreads();

    if (mat < 2) {
        u16* dst = (mat == 0) ? Qbh : Kbh;
        const int h8 = t >> 5, r = t & 31;
        const u16* src = Cs + r * CSTR + h8 * 16;
        u16* dp = dst + (size_t)h8 * (NA * 16) + (size_t)(r0b + r) * 16;
        *(bf16x8*)(dp)     = *(const bf16x8*)(src);
        *(bf16x8*)(dp + 8) = *(const bf16x8*)(src + 8);
    } else {
        const int d = t >> 1, s = t & 1;
        const int kb = r0b >> 6, ko = (r0b & 32) + s * 16;
        ushort8 v0, v1;
#pragma unroll
        for (int jj = 0; jj < 8; ++jj) v0[jj] = Cs[(s * 16 + jj) * CSTR + d];
#pragma unroll
        for (int jj = 0; jj < 8; ++jj) v1[jj] = Cs[(s * 16 + 8 + jj) * CSTR + d];
        u16* dp = VtB + (size_t)kb * 8192 + d * 64 + ko;
        *(ushort8*)(dp)     = v0;
        *(ushort8*)(dp + 8) = v1;
    }
}

// ---------------------------------------------------------------------------
// Kernel 2: attention partials. Grid (256 tiles, 4 key-splits), 512 thr =
// 8 waves, wave = one head. Mask pre-packed (Mp) -> 2KB LDS stage per block.
// S^T = K*Q^T. p = 2^S (no max subtraction). Per-t4 softmax path:
//   4 exp2 -> 2 v_cvt_pk_bf16_f32 -> AND with nibble-expanded mask (LDS
//   table) -> ds_write_b64.  lsum via ones-B MFMA on packed/masked P.
// kf loads for iter it+1 issued right after iter it's ST MFMAs.
// part[tile][split][head][272] = { O 16x16 f32, l 16 f32 }.
// ---------------------------------------------------------------------------
__global__ __launch_bounds__(512, 8) void attn(
    const u64* __restrict__ Mp,
    const u16* __restrict__ Qbh, const u16* __restrict__ Kbh, const u16* __restrict__ VtB,
    float* __restrict__ part)
{
    __shared__ __align__(16) u16 Pbuf[8 * 16 * PSTR];
    __shared__ __align__(8)  u64 Mwp[16 * 17];   // [query][word], padded stride
    __shared__ __align__(8)  u64 Mtab[16];       // nibble -> {lo16|hi16} x2 expand

    const int t = threadIdx.x;
    const int h = t >> 6;        // wave = head
    const int lane = t & 63;
    const int c = lane & 15;
    const int q = lane >> 4;
    const int tile = blockIdx.x, split = blockIdx.y;
    const int i0 = tile * 16;
    const int kt0 = split * 1024;

    // stage packed mask words: rows i0..i0+15, words split*16..+15
    if (t < 256) {
        const int row = t >> 4, w = t & 15;
        Mwp[row * 17 + w] = Mp[(size_t)(i0 + row) * 64 + (kt0 >> 6) + w];
    }
    if (t < 16) {
        const unsigned lo = ((t & 1) ? 0xFFFFu : 0u) | ((t & 2) ? 0xFFFF0000u : 0u);
        const unsigned hi = ((t & 4) ? 0xFFFFu : 0u) | ((t & 8) ? 0xFFFF0000u : 0u);
        Mtab[t] = (u64)lo | ((u64)hi << 32);
    }

    const u16* Qh = Qbh + (size_t)h * (NA * 16);
    const u16* Kh = Kbh + (size_t)h * (NA * 16);

    // Q B-fragment (K-halves duplicated; x2 folded into QSCALE); contiguous.
    const bf16x8 qf = *(const bf16x8*)(Qh + (size_t)(i0 + c) * 16 + (q & 1) * 8);

    // ones B-fragment for the lsum MFMA (all lanes = 1.0bf16)
    bf16x8 ones;
#pragma unroll
    for (int i = 0; i < 8; ++i) ones[i] = (short)0x3F80;

    __syncthreads();

    const f32x4 zero = {0.f, 0.f, 0.f, 0.f};
    f32x4 Oacc = zero;
    f32x4 Lacc = zero;
    u16* Pw = Pbuf + h * 16 * PSTR;

    // prologue: kf for iter 0
    bf16x8 kf[4];
#pragma unroll
    for (int t4 = 0; t4 < 4; ++t4)
        kf[t4] = *(const bf16x8*)(Kh + (size_t)(kt0 + t4 * 16 + c) * 16 + (q & 1) * 8);

#pragma unroll 1
    for (int it = 0; it < 16; ++it) {
        const int kt = kt0 + it * 64;
        const u16* Vb = VtB + (size_t)(kt >> 6) * 8192 + (h * 16 + c) * 64;

        // V B-fragments (contiguous 1KB per load across the wave)
        bf16x8 vf0 = *(const bf16x8*)(Vb + q * 8);
        bf16x8 vf1 = *(const bf16x8*)(Vb + 32 + q * 8);

        // S^T = K Q^T: lane (c,q) reg r = S[query i0+c][key kt+16*t4+4q+r]
        f32x4 ST[4];
#pragma unroll
        for (int t4 = 0; t4 < 4; ++t4)
            ST[t4] = __builtin_amdgcn_mfma_f32_16x16x32_bf16(kf[t4], qf, zero, 0, 0, 0);

        // prefetch next iter's kf (wraps to kt0 on last iter; data unused)
        const int ktn = kt0 + ((it + 1) & 15) * 64;
#pragma unroll
        for (int t4 = 0; t4 < 4; ++t4)
            kf[t4] = *(const bf16x8*)(Kh + (size_t)(ktn + t4 * 16 + c) * 16 + (q & 1) * 8);

        // mask bits: bit(16*t4+r) after shift = key 16*t4+4q+r
        u64 w = Mwp[c * 17 + it] >> (4 * q);
        unsigned mlo = (unsigned)w, mhi = (unsigned)(w >> 32);

#pragma unroll
        for (int t4 = 0; t4 < 4; ++t4) {
            const unsigned mw = (t4 < 2) ? mlo : mhi;
            const int sh = (t4 & 1) * 16;
            const unsigned nib = (mw >> sh) & 15u;
            float p0 = __builtin_amdgcn_exp2f(ST[t4][0]);
            float p1 = __builtin_amdgcn_exp2f(ST[t4][1]);
            float p2 = __builtin_amdgcn_exp2f(ST[t4][2]);
            float p3 = __builtin_amdgcn_exp2f(ST[t4][3]);
            unsigned lo, hi;
            asm("v_cvt_pk_bf16_f32 %0, %1, %2" : "=v"(lo) : "v"(p0), "v"(p1));
            asm("v_cvt_pk_bf16_f32 %0, %1, %2" : "=v"(hi) : "v"(p2), "v"(p3));
            const u64 mex = Mtab[nib];           // conflict-free (16 entries x b64)
            lo &= (unsigned)mex;
            hi &= (unsigned)(mex >> 32);
            *(uint2*)(Pw + c * PSTR + t4 * 16 + 4 * q) = make_uint2(lo, hi);
        }
        __asm__ volatile("" ::: "memory");
        __builtin_amdgcn_s_waitcnt(0xC07F);  // per-wave LDS drain (lgkmcnt 0)
        __asm__ volatile("" ::: "memory");

        // O += P @ V ; L += P @ ones (masked row-sums, replaces scalar lsum)
        bf16x8 pf0 = *(const bf16x8*)(Pw + c * PSTR + q * 8);
        bf16x8 pf1 = *(const bf16x8*)(Pw + c * PSTR + 32 + q * 8);
        Oacc = __builtin_amdgcn_mfma_f32_16x16x32_bf16(pf0, vf0, Oacc, 0, 0, 0);
        Oacc = __builtin_amdgcn_mfma_f32_16x16x32_bf16(pf1, vf1, Oacc, 0, 0, 0);
        Lacc = __builtin_amdgcn_mfma_f32_16x16x32_bf16(pf0, ones, Lacc, 0, 0, 0);
        Lacc = __builtin_amdgcn_mfma_f32_16x16x32_bf16(pf1, ones, Lacc, 0, 0, 0);
    }

    float* base = part + (size_t)((tile * 4 + split) * 8 + h) * 272;
#pragma unroll
    for (int r = 0; r < 4; ++r)
        base[(4 * q + r) * 16 + c] = Oacc[r];
    // Lacc: lane (c,q) reg r holds l[4q+r] (all c identical); c==0 lanes write
    if (c == 0) {
#pragma unroll
        for (int r = 0; r < 4; ++r)
            base[256 + 4 * q + r] = Lacc[r];
    }
}

// ---------------------------------------------------------------------------
// Kernel 3: combine 4 split partials, normalize, output projection via MFMA.
// ---------------------------------------------------------------------------
__global__ __launch_bounds__(256) void reduce_out(
    const float* __restrict__ part, const u16* __restrict__ Wf,
    float* __restrict__ out)
{
    __shared__ __align__(16) u16 xs[16 * CSTR];

    const int t = threadIdx.x;
    const int tile = blockIdx.x;
    const int i0 = tile * 16;
    const float* Pt = part + (size_t)tile * 4 * 8 * 272;

    {
        const int i = t >> 4, d = t & 15;
#pragma unroll
        for (int h = 0; h < 8; ++h) {
            float os = 0.f, ls = 0.f;
#pragma unroll
            for (int s = 0; s < 4; ++s) {
                const float* b = Pt + (size_t)(s * 8 + h) * 272;
                os += b[i * 16 + d];
                ls += b[256 + i];
            }
            xs[i * CSTR + h * 16 + d] = f2bf(os / ls);
        }
    }
    __syncthreads();

    const int wv = t >> 6, lane = t & 63;
    const int c = lane & 15, q = lane >> 4;
    const u16* WoB = Wf + 3 * 16384;

    bf16x8 af[4];
#pragma unroll
    for (int kk = 0; kk < 4; ++kk)
        af[kk] = *(const bf16x8*)(xs + c * CSTR + kk * 32 + q * 8);

    const f32x4 zero = {0.f, 0.f, 0.f, 0.f};
#pragma unroll
    for (int jj = 0; jj < 2; ++jj) {
        const int j0 = wv * 2 + jj;
        f32x4 acc = zero;
#pragma unroll
        for (int kk = 0; kk < 4; ++kk) {
            bf16x8 bf = *(const bf16x8*)(WoB + (j0 * 4 + kk) * 512 + c * 32 + q * 8);
            acc = __builtin_amdgcn_mfma_f32_16x16x32_bf16(af[kk], bf, acc, 0, 0, 0);
        }
#pragma unroll
        for (int r = 0; r < 4; ++r)
            out[(size_t)(i0 + 4 * q + r) * HS + j0 * 16 + c] = acc[r];
    }
}

extern "C" void kernel_launch(void* const* d_in, const int* in_sizes, int n_in,
                              void* d_out, int out_size, void* d_ws, size_t ws_size,
                              hipStream_t stream) {
    const float* query = (const float*)d_in[0];
    const float* key   = (const float*)d_in[1];
    const float* value = (const float*)d_in[2];
    const int*   mask  = (const int*)d_in[3];
    const float* Wq    = (const float*)d_in[4];
    const float* bq    = (const float*)d_in[5];
    const float* Wk    = (const float*)d_in[6];
    const float* bk    = (const float*)d_in[7];
    const float* Wv    = (const float*)d_in[8];
    const float* bv    = (const float*)d_in[9];
    const float* Wo    = (const float*)d_in[10];

    u16* Qbh = (u16*)d_ws;                     // 1 MB  [8][4096][16]
    u16* Kbh = Qbh + (size_t)NA * HS;          // 1 MB  [8][4096][16]
    u16* VtB = Kbh + (size_t)NA * HS;          // 1 MB  [64][128][64]
    u16* Wf  = VtB + (size_t)NA * HS;          // 128 KB
    float* bb    = (float*)(Wf + 4 * 16384);   // 1.5 KB
    u64*  Mp    = (u64*)(bb + 384);            // 2 MB   [4096][64] packed mask
    float* partb = (float*)(Mp + (size_t)NA * 64);  // 256*4*8*272 f32 = 8.9 MB

    cvt_w<<<64 + 1024, 256, 0, stream>>>(Wq, Wk, Wv, Wo, bq, bk, bv, mask, Wf, bb, Mp);
    proj_mfma<<<dim3(128, 3), 256, 0, stream>>>(query, key, value, Wf, bb, Qbh, Kbh, VtB);
    attn<<<dim3(256, 4), 512, 0, stream>>>(Mp, Qbh, Kbh, VtB, partb);
    reduce_out<<<256, 256, 0, stream>>>(partb, Wf, (float*)d_out);
}

// Round 2
// 194.719 us; speedup vs baseline: 1.0424x; 1.0424x over previous
//
#include <hip/hip_runtime.h>

#define NA 4096
#define HS 128
#define CSTR 136   // proj/reduce LDS row stride (bf16 elems)

typedef unsigned short u16;
typedef unsigned long long u64;
using bf16x8  = __attribute__((ext_vector_type(8))) short;
using f32x4   = __attribute__((ext_vector_type(4))) float;
using ushort8 = __attribute__((ext_vector_type(8))) unsigned short;
using u32x4   = __attribute__((ext_vector_type(4))) unsigned;

// 1/sqrt(dk)=0.25 * log2(e) * 0.5 (K-dim duplication in the 16x16x32 MFMA)
#define QSCALE 0.18033688011112042f

static __device__ __forceinline__ u16 f2bf(float f) {
    unsigned u = __builtin_bit_cast(unsigned, f);
    u += 0x7FFFu + ((u >> 16) & 1u);
    return (u16)(u >> 16);
}

// ---------------------------------------------------------------------------
// Kernel 0: weights -> bf16 in MFMA-fragment order:
//   Wf[mat][j0(8)][kk(4)][c(16)][q(4)][8]  (16384 elems per mat)
// mat: 0=Q(x QSCALE), 1=K, 2=V, 3=O. bb[mat][j] f32 biases (bq pre-scaled).
// ---------------------------------------------------------------------------
__global__ __launch_bounds__(256) void cvt_w(
    const float* __restrict__ Wq, const float* __restrict__ Wk,
    const float* __restrict__ Wv, const float* __restrict__ Wo,
    const float* __restrict__ bq, const float* __restrict__ bk,
    const float* __restrict__ bv,
    u16* __restrict__ Wf, float* __restrict__ bb)
{
    const int gid = blockIdx.x * 256 + threadIdx.x;   // 16384 threads
    const int e = gid * 4;
    const int mat = e >> 14, off = e & 16383;
    const float* src = (mat == 0) ? Wq : (mat == 1) ? Wk : (mat == 2) ? Wv : Wo;
    const float s = (mat == 0) ? QSCALE : 1.0f;
    float4 v = *(const float4*)(src + off);
    ushort4 o;
    o.x = f2bf(v.x * s); o.y = f2bf(v.y * s);
    o.z = f2bf(v.z * s); o.w = f2bf(v.w * s);
    const int j = off >> 7, k0 = off & 127;
    const int j0 = j >> 4, c = j & 15, kk = k0 >> 5, q = (k0 >> 3) & 3;
    const int tgt = mat * 16384 + ((j0 * 4 + kk) * 16 + c) * 32 + q * 8 + (k0 & 7);
    *(ushort4*)(Wf + tgt) = o;
    if (gid < 128)      bb[gid] = bq[gid] * QSCALE;
    else if (gid < 256) bb[gid] = bk[gid - 128];
    else if (gid < 384) bb[gid] = bv[gid - 256];
}

// ---------------------------------------------------------------------------
// Kernel 1 (merged): blocks 0..383 = Q/K/V projections via MFMA;
// blocks 384..1407 = ballot-pack mask -> Mp[row(4096)][word(64)] u64.
// Merging overlaps the 64 MB mask read with proj compute (was a serial stage).
// Outputs:
//   Qbh [head][4096][16]  natural row order
//   Kbh [head][4096][16]  rows PERMUTED within each 64-block by slot(k) so
//       attn's ST MFMA output lands P register-resident for the PV A-operand:
//       slot(k) = ((k>>5)*2+((k>>2)&1))*16 + ((k>>3)&3)*4 + (k&3)
//       => ST[t4] lane (c,q) reg r holds key 32*(t4>>1)+4*(t4&1)+8q+r
//   VtB [kb(64)][dim(128)][key(64)]  (PV B-fragment loads contiguous)
// ---------------------------------------------------------------------------
__global__ __launch_bounds__(256) void proj_mfma(
    const float* __restrict__ Xq, const float* __restrict__ Xk, const float* __restrict__ Xv,
    const u16* __restrict__ Wf, const float* __restrict__ bb,
    const int* __restrict__ mask,
    u16* __restrict__ Qbh, u16* __restrict__ Kbh, u16* __restrict__ VtB,
    u64* __restrict__ Mp)
{
    const int blk = blockIdx.x;
    const int t = threadIdx.x;

    if (blk >= 384) {               // ---- mask ballot-pack, natural bit order
        const int mb = blk - 384;   // 0..1023
        const int wv = t >> 6, lane = t & 63;
        const int row = mb * 4 + wv;            // one mask row per wave
        const int* mrow = mask + (size_t)row * NA;
        u64* orow = Mp + (size_t)row * 64;
#pragma unroll 8
        for (int w = 0; w < 64; ++w) {
            u64 b = __ballot(mrow[w * 64 + lane] != 0);
            if (lane == 0) orow[w] = b;
        }
        return;
    }

    const int mat = blk >> 7;
    const float* X = (mat == 0) ? Xq : (mat == 1) ? Xk : Xv;
    const u16* Wm = Wf + mat * 16384;
    const float* bm = bb + mat * 128;
    const int r0b = (blk & 127) * 32;

    __shared__ __align__(16) u16 Xs[32 * CSTR];
    __shared__ __align__(16) u16 Cs[32 * CSTR];

    // stage X coalesced: thread -> row t>>3, 16 cols at (t&7)*16
    {
        const int r = t >> 3, cb = (t & 7) * 16;
        const float* Xr = X + (size_t)(r0b + r) * HS + cb;
#pragma unroll
        for (int seg = 0; seg < 4; ++seg) {
            float4 f = *(const float4*)(Xr + seg * 4);
            ushort4 u;
            u.x = f2bf(f.x); u.y = f2bf(f.y); u.z = f2bf(f.z); u.w = f2bf(f.w);
            *(ushort4*)(Xs + r * CSTR + cb + seg * 4) = u;
        }
    }
    __syncthreads();

    const int wv = t >> 6, lane = t & 63;
    const int c = lane & 15, q = lane >> 4;
    const int rw = (wv & 1) * 16;        // wave row offset in block
    const int j0b = (wv >> 1) * 4;       // wave col group (4 j0 of 16 cols)

    bf16x8 af[4];
#pragma unroll
    for (int kk = 0; kk < 4; ++kk)
        af[kk] = *(const bf16x8*)(Xs + (rw + c) * CSTR + kk * 32 + q * 8);

    const f32x4 zero = {0.f, 0.f, 0.f, 0.f};
#pragma unroll
    for (int jj = 0; jj < 4; ++jj) {
        const int j0 = j0b + jj;
        f32x4 acc = zero;
#pragma unroll
        for (int kk = 0; kk < 4; ++kk) {
            bf16x8 bf = *(const bf16x8*)(Wm + (j0 * 4 + kk) * 512 + c * 32 + q * 8);
            acc = __builtin_amdgcn_mfma_f32_16x16x32_bf16(af[kk], bf, acc, 0, 0, 0);
        }
        const float bias = bm[j0 * 16 + c];
#pragma unroll
        for (int r = 0; r < 4; ++r)
            Cs[(rw + 4 * q + r) * CSTR + j0 * 16 + c] = f2bf(acc[r] + bias);
    }
    __syncthreads();

    if (mat < 2) {
        u16* dst = (mat == 0) ? Qbh : Kbh;
        const int h8 = t >> 5, r = t & 31;
        const u16* src = Cs + r * CSTR + h8 * 16;
        int drow = r0b + r;
        if (mat == 1) {   // permuted K row slot within the 64-row block
            const int k = (r0b & 32) + r;
            const int slot = ((k >> 5) * 2 + ((k >> 2) & 1)) * 16
                           + ((k >> 3) & 3) * 4 + (k & 3);
            drow = (r0b & ~63) + slot;
        }
        u16* dp = dst + (size_t)h8 * (NA * 16) + (size_t)drow * 16;
        *(bf16x8*)(dp)     = *(const bf16x8*)(src);
        *(bf16x8*)(dp + 8) = *(const bf16x8*)(src + 8);
    } else {
        const int d = t >> 1, s = t & 1;
        const int kb = r0b >> 6, ko = (r0b & 32) + s * 16;
        ushort8 v0, v1;
#pragma unroll
        for (int jj = 0; jj < 8; ++jj) v0[jj] = Cs[(s * 16 + jj) * CSTR + d];
#pragma unroll
        for (int jj = 0; jj < 8; ++jj) v1[jj] = Cs[(s * 16 + 8 + jj) * CSTR + d];
        u16* dp = VtB + (size_t)kb * 8192 + d * 64 + ko;
        *(ushort8*)(dp)     = v0;
        *(ushort8*)(dp + 8) = v1;
    }
}

// ---------------------------------------------------------------------------
// Kernel 2: attention partials. Grid (256 tiles, 4 key-splits), 512 thr =
// 8 waves, wave = one head. P never touches LDS: the K-row permutation makes
// ST[t4] lane (c,q) hold keys {8q..8q+7, 32+8q..32+8q+7}, which is exactly
// the PV A-fragment layout. Per iter: 4 ST MFMA -> 16 exp2 -> 8 cvt_pk ->
// mask AND (nibble->Mtab) -> 4 PV/L MFMA, all register-resident.
// part[tile][split][head][272] = { O 16x16 f32, l 16 f32 }.
// ---------------------------------------------------------------------------
__global__ __launch_bounds__(512, 4) void attn(
    const u64* __restrict__ Mp,
    const u16* __restrict__ Qbh, const u16* __restrict__ Kbh, const u16* __restrict__ VtB,
    float* __restrict__ part)
{
    __shared__ __align__(8)  u64 Mwp[16 * 17];   // [query][word], padded stride
    __shared__ __align__(8)  u64 Mtab[16];       // nibble -> {lo16|hi16} x2 expand

    const int t = threadIdx.x;
    const int h = t >> 6;        // wave = head
    const int lane = t & 63;
    const int c = lane & 15;
    const int q = lane >> 4;
    const int tile = blockIdx.x, split = blockIdx.y;
    const int i0 = tile * 16;
    const int kt0 = split * 1024;

    // stage packed mask words: rows i0..i0+15, words split*16..+15
    if (t < 256) {
        const int row = t >> 4, w = t & 15;
        Mwp[row * 17 + w] = Mp[(size_t)(i0 + row) * 64 + (kt0 >> 6) + w];
    }
    if (t < 16) {
        const unsigned lo = ((t & 1) ? 0xFFFFu : 0u) | ((t & 2) ? 0xFFFF0000u : 0u);
        const unsigned hi = ((t & 4) ? 0xFFFFu : 0u) | ((t & 8) ? 0xFFFF0000u : 0u);
        Mtab[t] = (u64)lo | ((u64)hi << 32);
    }

    const u16* Qh = Qbh + (size_t)h * (NA * 16);
    const u16* Kh = Kbh + (size_t)h * (NA * 16);

    // Q B-fragment (K-halves duplicated; x2 folded into QSCALE); contiguous.
    const bf16x8 qf = *(const bf16x8*)(Qh + (size_t)(i0 + c) * 16 + (q & 1) * 8);

    // ones B-fragment for the lsum MFMA (all lanes = 1.0bf16)
    bf16x8 ones;
#pragma unroll
    for (int i = 0; i < 8; ++i) ones[i] = (short)0x3F80;

    __syncthreads();

    const f32x4 zero = {0.f, 0.f, 0.f, 0.f};
    f32x4 Oacc = zero;
    f32x4 Lacc = zero;

    // prologue: kf for iter 0 (rows are permuted slots; addresses natural)
    bf16x8 kf[4];
#pragma unroll
    for (int t4 = 0; t4 < 4; ++t4)
        kf[t4] = *(const bf16x8*)(Kh + (size_t)(kt0 + t4 * 16 + c) * 16 + (q & 1) * 8);

#pragma unroll 1
    for (int it = 0; it < 16; ++it) {
        const int kt = kt0 + it * 64;
        const u16* Vb = VtB + (size_t)(kt >> 6) * 8192 + (h * 16 + c) * 64;

        // V B-fragments (contiguous 1KB per load across the wave)
        bf16x8 vf0 = *(const bf16x8*)(Vb + q * 8);
        bf16x8 vf1 = *(const bf16x8*)(Vb + 32 + q * 8);

        // S^T tiles; permuted K => lane (c,q) reg r = S[q_row c][key B(t4)+8q+r]
        f32x4 ST[4];
        __builtin_amdgcn_s_setprio(1);
#pragma unroll
        for (int t4 = 0; t4 < 4; ++t4)
            ST[t4] = __builtin_amdgcn_mfma_f32_16x16x32_bf16(kf[t4], qf, zero, 0, 0, 0);
        __builtin_amdgcn_s_setprio(0);

        // prefetch next iter's kf (wraps to kt0 on last iter; data unused)
        const int ktn = kt0 + ((it + 1) & 15) * 64;
#pragma unroll
        for (int t4 = 0; t4 < 4; ++t4)
            kf[t4] = *(const bf16x8*)(Kh + (size_t)(ktn + t4 * 16 + c) * 16 + (q & 1) * 8);

        // mask bits, natural order: key B(t4)+8q+r; B = 32*(t4>>1)+4*(t4&1)
        const u64 w = Mwp[c * 17 + it];
        const unsigned wa = (unsigned)(w >> (8 * q));          // keys 8q+...
        const unsigned wb = (unsigned)(w >> (32 + 8 * q));     // keys 32+8q+...

        unsigned pl[4], ph[4];
#pragma unroll
        for (int t4 = 0; t4 < 4; ++t4) {
            const unsigned nib = (((t4 & 2) ? wb : wa) >> ((t4 & 1) * 4)) & 15u;
            float p0 = __builtin_amdgcn_exp2f(ST[t4][0]);
            float p1 = __builtin_amdgcn_exp2f(ST[t4][1]);
            float p2 = __builtin_amdgcn_exp2f(ST[t4][2]);
            float p3 = __builtin_amdgcn_exp2f(ST[t4][3]);
            unsigned lo, hi;
            asm("v_cvt_pk_bf16_f32 %0, %1, %2" : "=v"(lo) : "v"(p0), "v"(p1));
            asm("v_cvt_pk_bf16_f32 %0, %1, %2" : "=v"(hi) : "v"(p2), "v"(p3));
            const u64 mex = Mtab[nib];           // conflict-light 16-entry table
            pl[t4] = lo & (unsigned)mex;
            ph[t4] = hi & (unsigned)(mex >> 32);
        }
        const u32x4 a0 = { pl[0], ph[0], pl[1], ph[1] };   // keys 8q+0..7
        const u32x4 a1 = { pl[2], ph[2], pl[3], ph[3] };   // keys 32+8q+0..7
        const bf16x8 pf0 = __builtin_bit_cast(bf16x8, a0);
        const bf16x8 pf1 = __builtin_bit_cast(bf16x8, a1);

        // O += P @ V ; L += P @ ones (masked row-sums)
        __builtin_amdgcn_s_setprio(1);
        Oacc = __builtin_amdgcn_mfma_f32_16x16x32_bf16(pf0, vf0, Oacc, 0, 0, 0);
        Oacc = __builtin_amdgcn_mfma_f32_16x16x32_bf16(pf1, vf1, Oacc, 0, 0, 0);
        Lacc = __builtin_amdgcn_mfma_f32_16x16x32_bf16(pf0, ones, Lacc, 0, 0, 0);
        Lacc = __builtin_amdgcn_mfma_f32_16x16x32_bf16(pf1, ones, Lacc, 0, 0, 0);
        __builtin_amdgcn_s_setprio(0);
    }

    float* base = part + (size_t)((tile * 4 + split) * 8 + h) * 272;
#pragma unroll
    for (int r = 0; r < 4; ++r)
        base[(4 * q + r) * 16 + c] = Oacc[r];
    // Lacc: lane (c,q) reg r holds l[4q+r] (all c identical); c==0 lanes write
    if (c == 0) {
#pragma unroll
        for (int r = 0; r < 4; ++r)
            base[256 + 4 * q + r] = Lacc[r];
    }
}

// ---------------------------------------------------------------------------
// Kernel 3: combine 4 split partials, normalize, output projection via MFMA.
// ---------------------------------------------------------------------------
__global__ __launch_bounds__(256) void reduce_out(
    const float* __restrict__ part, const u16* __restrict__ Wf,
    float* __restrict__ out)
{
    __shared__ __align__(16) u16 xs[16 * CSTR];

    const int t = threadIdx.x;
    const int tile = blockIdx.x;
    const int i0 = tile * 16;
    const float* Pt = part + (size_t)tile * 4 * 8 * 272;

    {
        const int i = t >> 4, d = t & 15;
#pragma unroll
        for (int h = 0; h < 8; ++h) {
            float os = 0.f, ls = 0.f;
#pragma unroll
            for (int s = 0; s < 4; ++s) {
                const float* b = Pt + (size_t)(s * 8 + h) * 272;
                os += b[i * 16 + d];
                ls += b[256 + i];
            }
            xs[i * CSTR + h * 16 + d] = f2bf(os / ls);
        }
    }
    __syncthreads();

    const int wv = t >> 6, lane = t & 63;
    const int c = lane & 15, q = lane >> 4;
    const u16* WoB = Wf + 3 * 16384;

    bf16x8 af[4];
#pragma unroll
    for (int kk = 0; kk < 4; ++kk)
        af[kk] = *(const bf16x8*)(xs + c * CSTR + kk * 32 + q * 8);

    const f32x4 zero = {0.f, 0.f, 0.f, 0.f};
#pragma unroll
    for (int jj = 0; jj < 2; ++jj) {
        const int j0 = wv * 2 + jj;
        f32x4 acc = zero;
#pragma unroll
        for (int kk = 0; kk < 4; ++kk) {
            bf16x8 bf = *(const bf16x8*)(WoB + (j0 * 4 + kk) * 512 + c * 32 + q * 8);
            acc = __builtin_amdgcn_mfma_f32_16x16x32_bf16(af[kk], bf, acc, 0, 0, 0);
        }
#pragma unroll
        for (int r = 0; r < 4; ++r)
            out[(size_t)(i0 + 4 * q + r) * HS + j0 * 16 + c] = acc[r];
    }
}

extern "C" void kernel_launch(void* const* d_in, const int* in_sizes, int n_in,
                              void* d_out, int out_size, void* d_ws, size_t ws_size,
                              hipStream_t stream) {
    const float* query = (const float*)d_in[0];
    const float* key   = (const float*)d_in[1];
    const float* value = (const float*)d_in[2];
    const int*   mask  = (const int*)d_in[3];
    const float* Wq    = (const float*)d_in[4];
    const float* bq    = (const float*)d_in[5];
    const float* Wk    = (const float*)d_in[6];
    const float* bk    = (const float*)d_in[7];
    const float* Wv    = (const float*)d_in[8];
    const float* bv    = (const float*)d_in[9];
    const float* Wo    = (const float*)d_in[10];

    u16* Qbh = (u16*)d_ws;                     // 1 MB  [8][4096][16]
    u16* Kbh = Qbh + (size_t)NA * HS;          // 1 MB  [8][4096][16] (permuted)
    u16* VtB = Kbh + (size_t)NA * HS;          // 1 MB  [64][128][64]
    u16* Wf  = VtB + (size_t)NA * HS;          // 128 KB
    float* bb    = (float*)(Wf + 4 * 16384);   // 1.5 KB
    u64*  Mp    = (u64*)(bb + 384);            // 2 MB   [4096][64] packed mask
    float* partb = (float*)(Mp + (size_t)NA * 64);  // 256*4*8*272 f32 = 8.9 MB

    cvt_w<<<64, 256, 0, stream>>>(Wq, Wk, Wv, Wo, bq, bk, bv, Wf, bb);
    proj_mfma<<<384 + 1024, 256, 0, stream>>>(query, key, value, Wf, bb, mask,
                                              Qbh, Kbh, VtB, Mp);
    attn<<<dim3(256, 4), 512, 0, stream>>>(Mp, Qbh, Kbh, VtB, partb);
    reduce_out<<<256, 256, 0, stream>>>(partb, Wf, (float*)d_out);
}

// Round 4
// 173.833 us; speedup vs baseline: 1.1676x; 1.1202x over previous
//
#include <hip/hip_runtime.h>

#define NA 4096
#define HS 128
#define CSTR 136   // proj/reduce LDS row stride (bf16 elems)

typedef unsigned short u16;
typedef unsigned long long u64;
using bf16x8  = __attribute__((ext_vector_type(8))) short;
using f32x4   = __attribute__((ext_vector_type(4))) float;
using ushort8 = __attribute__((ext_vector_type(8))) unsigned short;
using u32x4   = __attribute__((ext_vector_type(4))) unsigned;

// 1/sqrt(dk)=0.25 * log2(e) * 0.5 (K-dim duplication in the 16x16x32 MFMA)
#define QSCALE 0.18033688011112042f

static __device__ __forceinline__ u16 f2bf(float f) {
    unsigned u = __builtin_bit_cast(unsigned, f);
    u += 0x7FFFu + ((u >> 16) & 1u);
    return (u16)(u >> 16);
}

// ---------------------------------------------------------------------------
// Kernel 0: weights -> bf16 in MFMA-fragment order:
//   Wf[mat][j0(8)][kk(4)][c(16)][q(4)][8]  (16384 elems per mat)
// mat: 0=Q(x QSCALE), 1=K, 2=V, 3=O. bb[mat][j] f32 biases (bq pre-scaled).
// ---------------------------------------------------------------------------
__global__ __launch_bounds__(256) void cvt_w(
    const float* __restrict__ Wq, const float* __restrict__ Wk,
    const float* __restrict__ Wv, const float* __restrict__ Wo,
    const float* __restrict__ bq, const float* __restrict__ bk,
    const float* __restrict__ bv,
    u16* __restrict__ Wf, float* __restrict__ bb)
{
    const int gid = blockIdx.x * 256 + threadIdx.x;   // 16384 threads
    const int e = gid * 4;
    const int mat = e >> 14, off = e & 16383;
    const float* src = (mat == 0) ? Wq : (mat == 1) ? Wk : (mat == 2) ? Wv : Wo;
    const float s = (mat == 0) ? QSCALE : 1.0f;
    float4 v = *(const float4*)(src + off);
    ushort4 o;
    o.x = f2bf(v.x * s); o.y = f2bf(v.y * s);
    o.z = f2bf(v.z * s); o.w = f2bf(v.w * s);
    const int j = off >> 7, k0 = off & 127;
    const int j0 = j >> 4, c = j & 15, kk = k0 >> 5, q = (k0 >> 3) & 3;
    const int tgt = mat * 16384 + ((j0 * 4 + kk) * 16 + c) * 32 + q * 8 + (k0 & 7);
    *(ushort4*)(Wf + tgt) = o;
    if (gid < 128)      bb[gid] = bq[gid] * QSCALE;
    else if (gid < 256) bb[gid] = bk[gid - 128];
    else if (gid < 384) bb[gid] = bv[gid - 256];
}

// ---------------------------------------------------------------------------
// Kernel 1 (merged): blocks 0..383 = Q/K/V projections via MFMA;
// blocks 384..1407 = mask pack -> Mp[row(4096)][word(64)] u64.
// Pack is latency-tolerant: each LANE builds one full u64 word from 64
// consecutive ints via 16 independent int4 loads staged to registers
// (no ballot, no divergent store; 8B/lane coalesced output).
// BISECT NOTE (r4): pack kept from r3; attn reverted to r2-exact.
// Outputs:
//   Qbh [head][4096][16]  natural row order
//   Kbh [head][4096][16]  rows PERMUTED within each 64-block by slot(k) so
//       attn's ST MFMA output lands P register-resident for the PV A-operand:
//       slot(k) = ((k>>5)*2+((k>>2)&1))*16 + ((k>>3)&3)*4 + (k&3)
//       => ST[t4] lane (c,q) reg r holds key 32*(t4>>1)+4*(t4&1)+8q+r
//   VtB [kb(64)][dim(128)][key(64)]  (PV B-fragment loads contiguous)
// ---------------------------------------------------------------------------
__global__ __launch_bounds__(256) void proj_mfma(
    const float* __restrict__ Xq, const float* __restrict__ Xk, const float* __restrict__ Xv,
    const u16* __restrict__ Wf, const float* __restrict__ bb,
    const int* __restrict__ mask,
    u16* __restrict__ Qbh, u16* __restrict__ Kbh, u16* __restrict__ VtB,
    u64* __restrict__ Mp)
{
    const int blk = blockIdx.x;
    const int t = threadIdx.x;

    if (blk >= 384) {               // ---- mask pack, per-lane word build
        const int mb = blk - 384;   // 0..1023
        const int wv = t >> 6, lane = t & 63;
        const int row = mb * 4 + wv;            // one mask row per wave
        const int* lp = mask + (size_t)row * NA + lane * 64;
        int4 v[16];
#pragma unroll
        for (int j = 0; j < 16; ++j) v[j] = *(const int4*)(lp + j * 4);
        u64 word = 0;
#pragma unroll
        for (int j = 0; j < 16; ++j) {
            const u64 nib = (u64)((v[j].x != 0 ? 1u : 0u) | (v[j].y != 0 ? 2u : 0u)
                                | (v[j].z != 0 ? 4u : 0u) | (v[j].w != 0 ? 8u : 0u));
            word |= nib << (4 * j);
        }
        Mp[(size_t)row * 64 + lane] = word;
        return;
    }

    const int mat = blk >> 7;
    const float* X = (mat == 0) ? Xq : (mat == 1) ? Xk : Xv;
    const u16* Wm = Wf + mat * 16384;
    const float* bm = bb + mat * 128;
    const int r0b = (blk & 127) * 32;

    __shared__ __align__(16) u16 Xs[32 * CSTR];
    __shared__ __align__(16) u16 Cs[32 * CSTR];

    // stage X coalesced: thread -> row t>>3, 16 cols at (t&7)*16
    {
        const int r = t >> 3, cb = (t & 7) * 16;
        const float* Xr = X + (size_t)(r0b + r) * HS + cb;
#pragma unroll
        for (int seg = 0; seg < 4; ++seg) {
            float4 f = *(const float4*)(Xr + seg * 4);
            ushort4 u;
            u.x = f2bf(f.x); u.y = f2bf(f.y); u.z = f2bf(f.z); u.w = f2bf(f.w);
            *(ushort4*)(Xs + r * CSTR + cb + seg * 4) = u;
        }
    }
    __syncthreads();

    const int wv = t >> 6, lane = t & 63;
    const int c = lane & 15, q = lane >> 4;
    const int rw = (wv & 1) * 16;        // wave row offset in block
    const int j0b = (wv >> 1) * 4;       // wave col group (4 j0 of 16 cols)

    bf16x8 af[4];
#pragma unroll
    for (int kk = 0; kk < 4; ++kk)
        af[kk] = *(const bf16x8*)(Xs + (rw + c) * CSTR + kk * 32 + q * 8);

    const f32x4 zero = {0.f, 0.f, 0.f, 0.f};
#pragma unroll
    for (int jj = 0; jj < 4; ++jj) {
        const int j0 = j0b + jj;
        f32x4 acc = zero;
#pragma unroll
        for (int kk = 0; kk < 4; ++kk) {
            bf16x8 bf = *(const bf16x8*)(Wm + (j0 * 4 + kk) * 512 + c * 32 + q * 8);
            acc = __builtin_amdgcn_mfma_f32_16x16x32_bf16(af[kk], bf, acc, 0, 0, 0);
        }
        const float bias = bm[j0 * 16 + c];
#pragma unroll
        for (int r = 0; r < 4; ++r)
            Cs[(rw + 4 * q + r) * CSTR + j0 * 16 + c] = f2bf(acc[r] + bias);
    }
    __syncthreads();

    if (mat < 2) {
        u16* dst = (mat == 0) ? Qbh : Kbh;
        const int h8 = t >> 5, r = t & 31;
        const u16* src = Cs + r * CSTR + h8 * 16;
        int drow = r0b + r;
        if (mat == 1) {   // permuted K row slot within the 64-row block
            const int k = (r0b & 32) + r;
            const int slot = ((k >> 5) * 2 + ((k >> 2) & 1)) * 16
                           + ((k >> 3) & 3) * 4 + (k & 3);
            drow = (r0b & ~63) + slot;
        }
        u16* dp = dst + (size_t)h8 * (NA * 16) + (size_t)drow * 16;
        *(bf16x8*)(dp)     = *(const bf16x8*)(src);
        *(bf16x8*)(dp + 8) = *(const bf16x8*)(src + 8);
    } else {
        const int d = t >> 1, s = t & 1;
        const int kb = r0b >> 6, ko = (r0b & 32) + s * 16;
        ushort8 v0, v1;
#pragma unroll
        for (int jj = 0; jj < 8; ++jj) v0[jj] = Cs[(s * 16 + jj) * CSTR + d];
#pragma unroll
        for (int jj = 0; jj < 8; ++jj) v1[jj] = Cs[(s * 16 + 8 + jj) * CSTR + d];
        u16* dp = VtB + (size_t)kb * 8192 + d * 64 + ko;
        *(ushort8*)(dp)     = v0;
        *(ushort8*)(dp + 8) = v1;
    }
}

// ---------------------------------------------------------------------------
// Kernel 2: attention partials — EXACT round-2 configuration (passed twice).
// Grid (256 tiles, 4 key-splits), 512 thr = 8 waves, wave = one head.
// P never touches LDS: the K-row permutation makes ST[t4] lane (c,q) hold
// keys {8q..8q+7, 32+8q..32+8q+7} = the PV A-fragment layout. Per iter:
// 4 ST MFMA -> 16 exp2 -> 8 cvt_pk -> mask AND -> 4 PV/L MFMA, all in regs.
// part[tile][split][head][272] = { O 16x16 f32, l 16 f32 }.
// ---------------------------------------------------------------------------
__global__ __launch_bounds__(512, 4) void attn(
    const u64* __restrict__ Mp,
    const u16* __restrict__ Qbh, const u16* __restrict__ Kbh, const u16* __restrict__ VtB,
    float* __restrict__ part)
{
    __shared__ __align__(8)  u64 Mwp[16 * 17];   // [query][word], padded stride
    __shared__ __align__(8)  u64 Mtab[16];       // nibble -> {lo16|hi16} x2 expand

    const int t = threadIdx.x;
    const int h = t >> 6;        // wave = head
    const int lane = t & 63;
    const int c = lane & 15;
    const int q = lane >> 4;
    const int tile = blockIdx.x, split = blockIdx.y;
    const int i0 = tile * 16;
    const int kt0 = split * 1024;

    // stage packed mask words: rows i0..i0+15, words split*16..+15
    if (t < 256) {
        const int row = t >> 4, w = t & 15;
        Mwp[row * 17 + w] = Mp[(size_t)(i0 + row) * 64 + (kt0 >> 6) + w];
    }
    if (t < 16) {
        const unsigned lo = ((t & 1) ? 0xFFFFu : 0u) | ((t & 2) ? 0xFFFF0000u : 0u);
        const unsigned hi = ((t & 4) ? 0xFFFFu : 0u) | ((t & 8) ? 0xFFFF0000u : 0u);
        Mtab[t] = (u64)lo | ((u64)hi << 32);
    }

    const u16* Qh = Qbh + (size_t)h * (NA * 16);
    const u16* Kh = Kbh + (size_t)h * (NA * 16);

    // Q B-fragment (K-halves duplicated; x2 folded into QSCALE); contiguous.
    const bf16x8 qf = *(const bf16x8*)(Qh + (size_t)(i0 + c) * 16 + (q & 1) * 8);

    // ones B-fragment for the lsum MFMA (all lanes = 1.0bf16)
    bf16x8 ones;
#pragma unroll
    for (int i = 0; i < 8; ++i) ones[i] = (short)0x3F80;

    __syncthreads();

    const f32x4 zero = {0.f, 0.f, 0.f, 0.f};
    f32x4 Oacc = zero;
    f32x4 Lacc = zero;

    // prologue: kf for iter 0 (rows are permuted slots; addresses natural)
    bf16x8 kf[4];
#pragma unroll
    for (int t4 = 0; t4 < 4; ++t4)
        kf[t4] = *(const bf16x8*)(Kh + (size_t)(kt0 + t4 * 16 + c) * 16 + (q & 1) * 8);

#pragma unroll 1
    for (int it = 0; it < 16; ++it) {
        const int kt = kt0 + it * 64;
        const u16* Vb = VtB + (size_t)(kt >> 6) * 8192 + (h * 16 + c) * 64;

        // V B-fragments (contiguous 1KB per load across the wave)
        bf16x8 vf0 = *(const bf16x8*)(Vb + q * 8);
        bf16x8 vf1 = *(const bf16x8*)(Vb + 32 + q * 8);

        // S^T tiles; permuted K => lane (c,q) reg r = S[q_row c][key B(t4)+8q+r]
        f32x4 ST[4];
        __builtin_amdgcn_s_setprio(1);
#pragma unroll
        for (int t4 = 0; t4 < 4; ++t4)
            ST[t4] = __builtin_amdgcn_mfma_f32_16x16x32_bf16(kf[t4], qf, zero, 0, 0, 0);
        __builtin_amdgcn_s_setprio(0);

        // prefetch next iter's kf (wraps to kt0 on last iter; data unused)
        const int ktn = kt0 + ((it + 1) & 15) * 64;
#pragma unroll
        for (int t4 = 0; t4 < 4; ++t4)
            kf[t4] = *(const bf16x8*)(Kh + (size_t)(ktn + t4 * 16 + c) * 16 + (q & 1) * 8);

        // mask bits, natural order: key B(t4)+8q+r; B = 32*(t4>>1)+4*(t4&1)
        const u64 w = Mwp[c * 17 + it];
        const unsigned wa = (unsigned)(w >> (8 * q));          // keys 8q+...
        const unsigned wb = (unsigned)(w >> (32 + 8 * q));     // keys 32+8q+...

        unsigned pl[4], ph[4];
#pragma unroll
        for (int t4 = 0; t4 < 4; ++t4) {
            const unsigned nib = (((t4 & 2) ? wb : wa) >> ((t4 & 1) * 4)) & 15u;
            float p0 = __builtin_amdgcn_exp2f(ST[t4][0]);
            float p1 = __builtin_amdgcn_exp2f(ST[t4][1]);
            float p2 = __builtin_amdgcn_exp2f(ST[t4][2]);
            float p3 = __builtin_amdgcn_exp2f(ST[t4][3]);
            unsigned lo, hi;
            asm("v_cvt_pk_bf16_f32 %0, %1, %2" : "=v"(lo) : "v"(p0), "v"(p1));
            asm("v_cvt_pk_bf16_f32 %0, %1, %2" : "=v"(hi) : "v"(p2), "v"(p3));
            const u64 mex = Mtab[nib];           // conflict-light 16-entry table
            pl[t4] = lo & (unsigned)mex;
            ph[t4] = hi & (unsigned)(mex >> 32);
        }
        const u32x4 a0 = { pl[0], ph[0], pl[1], ph[1] };   // keys 8q+0..7
        const u32x4 a1 = { pl[2], ph[2], pl[3], ph[3] };   // keys 32+8q+0..7
        const bf16x8 pf0 = __builtin_bit_cast(bf16x8, a0);
        const bf16x8 pf1 = __builtin_bit_cast(bf16x8, a1);

        // O += P @ V ; L += P @ ones (masked row-sums)
        __builtin_amdgcn_s_setprio(1);
        Oacc = __builtin_amdgcn_mfma_f32_16x16x32_bf16(pf0, vf0, Oacc, 0, 0, 0);
        Oacc = __builtin_amdgcn_mfma_f32_16x16x32_bf16(pf1, vf1, Oacc, 0, 0, 0);
        Lacc = __builtin_amdgcn_mfma_f32_16x16x32_bf16(pf0, ones, Lacc, 0, 0, 0);
        Lacc = __builtin_amdgcn_mfma_f32_16x16x32_bf16(pf1, ones, Lacc, 0, 0, 0);
        __builtin_amdgcn_s_setprio(0);
    }

    float* base = part + (size_t)((tile * 4 + split) * 8 + h) * 272;
#pragma unroll
    for (int r = 0; r < 4; ++r)
        base[(4 * q + r) * 16 + c] = Oacc[r];
    // Lacc: lane (c,q) reg r holds l[4q+r] (all c identical); c==0 lanes write
    if (c == 0) {
#pragma unroll
        for (int r = 0; r < 4; ++r)
            base[256 + 4 * q + r] = Lacc[r];
    }
}

// ---------------------------------------------------------------------------
// Kernel 3: combine 4 split partials, normalize, output projection via MFMA.
// ---------------------------------------------------------------------------
__global__ __launch_bounds__(256) void reduce_out(
    const float* __restrict__ part, const u16* __restrict__ Wf,
    float* __restrict__ out)
{
    __shared__ __align__(16) u16 xs[16 * CSTR];

    const int t = threadIdx.x;
    const int tile = blockIdx.x;
    const int i0 = tile * 16;
    const float* Pt = part + (size_t)tile * 4 * 8 * 272;

    {
        const int i = t >> 4, d = t & 15;
#pragma unroll
        for (int h = 0; h < 8; ++h) {
            float os = 0.f, ls = 0.f;
#pragma unroll
            for (int s = 0; s < 4; ++s) {
                const float* b = Pt + (size_t)(s * 8 + h) * 272;
                os += b[i * 16 + d];
                ls += b[256 + i];
            }
            xs[i * CSTR + h * 16 + d] = f2bf(os / ls);
        }
    }
    __syncthreads();

    const int wv = t >> 6, lane = t & 63;
    const int c = lane & 15, q = lane >> 4;
    const u16* WoB = Wf + 3 * 16384;

    bf16x8 af[4];
#pragma unroll
    for (int kk = 0; kk < 4; ++kk)
        af[kk] = *(const bf16x8*)(xs + c * CSTR + kk * 32 + q * 8);

    const f32x4 zero = {0.f, 0.f, 0.f, 0.f};
#pragma unroll
    for (int jj = 0; jj < 2; ++jj) {
        const int j0 = wv * 2 + jj;
        f32x4 acc = zero;
#pragma unroll
        for (int kk = 0; kk < 4; ++kk) {
            bf16x8 bf = *(const bf16x8*)(WoB + (j0 * 4 + kk) * 512 + c * 32 + q * 8);
            acc = __builtin_amdgcn_mfma_f32_16x16x32_bf16(af[kk], bf, acc, 0, 0, 0);
        }
#pragma unroll
        for (int r = 0; r < 4; ++r)
            out[(size_t)(i0 + 4 * q + r) * HS + j0 * 16 + c] = acc[r];
    }
}

extern "C" void kernel_launch(void* const* d_in, const int* in_sizes, int n_in,
                              void* d_out, int out_size, void* d_ws, size_t ws_size,
                              hipStream_t stream) {
    const float* query = (const float*)d_in[0];
    const float* key   = (const float*)d_in[1];
    const float* value = (const float*)d_in[2];
    const int*   mask  = (const int*)d_in[3];
    const float* Wq    = (const float*)d_in[4];
    const float* bq    = (const float*)d_in[5];
    const float* Wk    = (const float*)d_in[6];
    const float* bk    = (const float*)d_in[7];
    const float* Wv    = (const float*)d_in[8];
    const float* bv    = (const float*)d_in[9];
    const float* Wo    = (const float*)d_in[10];

    u16* Qbh = (u16*)d_ws;                     // 1 MB  [8][4096][16]
    u16* Kbh = Qbh + (size_t)NA * HS;          // 1 MB  [8][4096][16] (permuted)
    u16* VtB = Kbh + (size_t)NA * HS;          // 1 MB  [64][128][64]
    u16* Wf  = VtB + (size_t)NA * HS;          // 128 KB
    float* bb    = (float*)(Wf + 4 * 16384);   // 1.5 KB
    u64*  Mp    = (u64*)(bb + 384);            // 2 MB   [4096][64] packed mask
    float* partb = (float*)(Mp + (size_t)NA * 64);  // 256*4*8*272 f32 = 8.9 MB

    cvt_w<<<64, 256, 0, stream>>>(Wq, Wk, Wv, Wo, bq, bk, bv, Wf, bb);
    proj_mfma<<<384 + 1024, 256, 0, stream>>>(query, key, value, Wf, bb, mask,
                                              Qbh, Kbh, VtB, Mp);
    attn<<<dim3(256, 4), 512, 0, stream>>>(Mp, Qbh, Kbh, VtB, partb);
    reduce_out<<<256, 256, 0, stream>>>(partb, Wf, (float*)d_out);
}